// Round 7
// baseline (838.620 us; speedup 1.0000x reference)
//
#include <hip/hip_runtime.h>
#include <math.h>

#define N_NODES 100000
#define N_EDGES 1600000
#define N_IN 256
#define N_OUT 64

#define RPB 64                                    // rows per bucket
#define NBUCKETS ((N_NODES + RPB - 1) / RPB)      // 1563
#define EPB 2048                                  // edges per scatter block
#define NBLK ((N_EDGES + EPB - 1) / EPB)          // 782

// ws layout (bytes). Total ~25.6 MB.
// gposT aliases hbf: last read in scat2, hbf first written in gemm (later in
// stream order). histT aliases edges: dead after scanA, edges written in scat2.
#define WS_HBF    0           // bf16 h [100000][64]            12,800,000 B
#define WS_GP     WS_HBF      // u16 gposT[782][1563] (alias)    2,444,532 B
#define WS_WT     12800000    // bf16 W^T swizzled image            32,768 B
#define WS_BTOT   12832768    // int btot[1563]                      6,400 B
#define WS_BOFF   12839168    // int boffs[1564]                     6,400 B
#define WS_EDGES  12845568    // int2 bucketed edges[1600000]   12,800,000 B
#define WS_HT     WS_EDGES    // u16 histT[782][1563] (alias)    2,444,532 B

typedef __attribute__((ext_vector_type(8))) __bf16 bf16x8;
typedef __attribute__((ext_vector_type(4))) float f32x4;

static __device__ __forceinline__ unsigned short f2bf(float f) {
    union { float f; unsigned int u; } a; a.f = f;
    unsigned int u = a.u;
    return (unsigned short)((u + 0x7FFFu + ((u >> 16) & 1u)) >> 16); // RNE
}
static __device__ __forceinline__ float bf2f(unsigned short h) {
    union { unsigned int u; float f; } a; a.u = ((unsigned int)h) << 16;
    return a.f;
}

// ---------------------------------------------------------------------------
// W [256][64] fp32 -> W^T bf16 swizzled LDS image (see gemm_kernel).
// ---------------------------------------------------------------------------
__global__ __launch_bounds__(256) void wconv_kernel(const float* __restrict__ W,
                                                    unsigned short* __restrict__ wt) {
    const int g = blockIdx.x * 256 + threadIdx.x;   // 0..16383
    const int k = g >> 6, n = g & 63;
    const unsigned short v = f2bf(W[k * N_OUT + n]);
    const unsigned m = (unsigned)k >> 3;
    const unsigned byte = (unsigned)n * 512u + ((m ^ ((unsigned)n & 7u)) << 4);
    wt[byte / 2 + (k & 7)] = v;
}

// ---------------------------------------------------------------------------
// GEMM h = x @ W + b via v_mfma_f32_16x16x32_bf16, h stored bf16.
// ---------------------------------------------------------------------------
__global__ __launch_bounds__(256) void gemm_kernel(const float* __restrict__ x,
                                                   const float4* __restrict__ wt,
                                                   const float* __restrict__ bias,
                                                   unsigned short* __restrict__ hbf) {
    __shared__ unsigned short Wlds[N_IN * N_OUT]; // 32 KB, swizzled image
    const int t = threadIdx.x;
#pragma unroll
    for (int i = 0; i < 8; ++i)
        reinterpret_cast<float4*>(Wlds)[t + i * 256] = wt[t + i * 256];
    __syncthreads();

    const int wave = t >> 6, lane = t & 63;
    const int lrow = lane & 15, q = lane >> 4;
    const int r0 = blockIdx.x * 64 + wave * 16;
    int row = r0 + lrow;
    if (row >= N_NODES) row = N_NODES - 1;       // clamp loads; stores guarded
    const float* xp = x + (size_t)row * N_IN + q * 8;

    const char* ldsb = reinterpret_cast<const char*>(Wlds);
    unsigned colbase[4], colx[4];
#pragma unroll
    for (int c = 0; c < 4; ++c) {
        const unsigned col = c * 16 + lrow;
        colbase[c] = col * 512u;
        colx[c] = col & 7u;
    }

    f32x4 acc[4];
#pragma unroll
    for (int c = 0; c < 4; ++c) acc[c] = (f32x4){0.f, 0.f, 0.f, 0.f};

#pragma unroll
    for (int ks = 0; ks < 8; ++ks) {
        const float4 a0 = *reinterpret_cast<const float4*>(xp + ks * 32);
        const float4 a1 = *reinterpret_cast<const float4*>(xp + ks * 32 + 4);
        union { bf16x8 v; unsigned short u[8]; } af;
        af.u[0] = f2bf(a0.x); af.u[1] = f2bf(a0.y);
        af.u[2] = f2bf(a0.z); af.u[3] = f2bf(a0.w);
        af.u[4] = f2bf(a1.x); af.u[5] = f2bf(a1.y);
        af.u[6] = f2bf(a1.z); af.u[7] = f2bf(a1.w);
        const unsigned m = ks * 4 + q;
#pragma unroll
        for (int c = 0; c < 4; ++c) {
            const unsigned byte = colbase[c] + ((m ^ colx[c]) << 4);
            const bf16x8 bv = *reinterpret_cast<const bf16x8*>(ldsb + byte);
            acc[c] = __builtin_amdgcn_mfma_f32_16x16x32_bf16(af.v, bv, acc[c], 0, 0, 0);
        }
    }

#pragma unroll
    for (int c = 0; c < 4; ++c) {
        const int col = c * 16 + lrow;
        const float bv = bias[col];
#pragma unroll
        for (int mm = 0; mm < 4; ++mm) {
            const int rr = r0 + q * 4 + mm;
            if (rr < N_NODES)
                hbf[(size_t)rr * N_OUT + col] = f2bf(acc[c][mm] + bv);
        }
    }
}

// ---------------- scatter pass 1: per-block bucket histogram ---------------
__global__ __launch_bounds__(256) void hist2_kernel(const int* __restrict__ er,
                                                    unsigned short* __restrict__ histT) {
    __shared__ int lh[NBUCKETS];
    const int blk = blockIdx.x, t = threadIdx.x;
    const int e0 = blk * EPB;
    const int cnt = min(EPB, N_EDGES - e0);
    for (int i = t; i < NBUCKETS; i += 256) lh[i] = 0;
    __syncthreads();
#pragma unroll
    for (int j = 0; j < EPB / 256; ++j) {
        const int i = t + j * 256;
        if (i < cnt) atomicAdd(&lh[er[e0 + i] >> 6], 1);
    }
    __syncthreads();
    for (int i = t; i < NBUCKETS; i += 256)
        histT[(size_t)blk * NBUCKETS + i] = (unsigned short)lh[i];
}

// ---------------- scatter pass 2: within-bucket scan over blocks -----------
// one wave per bucket: exclusive scan of histT[*][b] over 782 blocks ->
// u16 gposT[blk][b] (within-bucket offset), int btot[b].
__global__ __launch_bounds__(256) void scanA_kernel(const unsigned short* __restrict__ histT,
                                                    unsigned short* __restrict__ gposT,
                                                    int* __restrict__ btot) {
    const int w = (int)((blockIdx.x * 256u + threadIdx.x) >> 6);  // bucket
    const int lane = threadIdx.x & 63;
    if (w >= NBUCKETS) return;                    // wave-uniform
    int running = 0;
#pragma unroll
    for (int c = 0; c < (NBLK + 63) / 64; ++c) {
        const int idx = c * 64 + lane;            // block index
        const int v = (idx < NBLK) ? (int)histT[(size_t)idx * NBUCKETS + w] : 0;
        int inc = v;
#pragma unroll
        for (int d = 1; d < 64; d <<= 1) {
            const int u = __shfl_up(inc, d, 64);
            if (lane >= d) inc += u;
        }
        if (idx < NBLK)
            gposT[(size_t)idx * NBUCKETS + w] = (unsigned short)(running + inc - v);
        running += __shfl(inc, 63, 64);
    }
    if (lane == 0) btot[w] = running;
}

// ---------------- scatter pass 3: cross-bucket scan (1 block) --------------
__global__ __launch_bounds__(1024) void bscan_kernel(const int* __restrict__ btot,
                                                     int* __restrict__ boffs) {
    __shared__ int s[1024];
    const int t = threadIdx.x;
    const int i0 = 2 * t, i1 = 2 * t + 1;
    const int a = (i0 < NBUCKETS) ? btot[i0] : 0;
    const int bv = (i1 < NBUCKETS) ? btot[i1] : 0;
    s[t] = a + bv; __syncthreads();
#pragma unroll
    for (int d = 1; d < 1024; d <<= 1) {
        const int u = (t >= d) ? s[t - d] : 0;
        __syncthreads();
        s[t] += u;
        __syncthreads();
    }
    const int excl = s[t] - (a + bv);
    if (i0 < NBUCKETS) boffs[i0] = excl;
    if (i1 < NBUCKETS) boffs[i1] = excl + a;
    if (t == 0) boffs[NBUCKETS] = N_EDGES;
}

// ---------------- scatter pass 4: direct exact-position scatter ------------
// rank via LDS int cursor; one direct 8B global write per edge. No global
// atomics, no staging buffer, no barriers in the hot path.
__global__ __launch_bounds__(256) void scat2_kernel(const int* __restrict__ er,
                                                    const int* __restrict__ ec,
                                                    const float* __restrict__ ev,
                                                    const unsigned short* __restrict__ gposT,
                                                    const int* __restrict__ boffs,
                                                    int2* __restrict__ edges) {
    __shared__ int lcur[NBUCKETS];    // 6.25 KB
    const int blk = blockIdx.x, t = threadIdx.x;
    const int e0 = blk * EPB;
    const int cnt = min(EPB, N_EDGES - e0);
    for (int i = t; i < NBUCKETS; i += 256) lcur[i] = 0;
    __syncthreads();
#pragma unroll
    for (int j = 0; j < EPB / 256; ++j) {
        const int i = t + j * 256;
        if (i < cnt) {
            const int r = er[e0 + i];
            const int bkt = r >> 6;
            const int rank = atomicAdd(&lcur[bkt], 1);
            const int pos = boffs[bkt] + (int)gposT[(size_t)blk * NBUCKETS + bkt] + rank;
            edges[pos] = make_int2(ec[e0 + i] | ((r & 63) << 17), __float_as_int(ev[e0 + i]));
        }
    }
}

// ------------------- bucket aggregation + fused ELU ------------------------
// one block (4 waves) per 64-row bucket; 16 KB LDS fp32 accumulator fed by
// native ds_add_f32 (unsafeAtomicAdd — fire-and-forget, no CAS). 8-deep ILP
// gathers of h rows (L2/L3-resident). No sorting, no hot-path barriers.
__global__ __launch_bounds__(256) void bagg_kernel(const int* __restrict__ boffs,
                                                   const int2* __restrict__ edges,
                                                   const unsigned short* __restrict__ hbf,
                                                   float* __restrict__ out) {
    __shared__ float accum[RPB * N_OUT];   // 16 KB
    const int b = blockIdx.x;
    const int t = threadIdx.x;
    const int wave = t >> 6, lane = t & 63;
#pragma unroll
    for (int i = 0; i < (RPB * N_OUT) / (256 * 4); ++i)
        reinterpret_cast<float4*>(accum)[t + i * 256] = (float4){0.f, 0.f, 0.f, 0.f};
    __syncthreads();

    const int s = boffs[b], e = boffs[b + 1];
    const int n = e - s;
    const int nmain = n & ~31;             // main: groups of 32 (4 waves x 8)

    for (int i = s + wave * 8; i < s + nmain; i += 32) {
        int2 E[8];
#pragma unroll
        for (int j = 0; j < 8; ++j) E[j] = edges[i + j];
        float hv[8];
#pragma unroll
        for (int j = 0; j < 8; ++j)
            hv[j] = bf2f(hbf[(size_t)(E[j].x & 0x1FFFF) * N_OUT + lane]);
#pragma unroll
        for (int j = 0; j < 8; ++j)
            unsafeAtomicAdd(&accum[(E[j].x >> 17) * N_OUT + lane],
                            __int_as_float(E[j].y) * hv[j]);
    }
    // tail (<32 edges): wave-parallel singles
    for (int i = s + nmain + wave; i < e; i += 4) {
        const int2 E = edges[i];
        const float hv = bf2f(hbf[(size_t)(E.x & 0x1FFFF) * N_OUT + lane]);
        unsafeAtomicAdd(&accum[(E.x >> 17) * N_OUT + lane], __int_as_float(E.y) * hv);
    }
    __syncthreads();

    // ELU + coalesced writeout
    const int row0 = b * RPB;
    for (int r = wave; r < RPB; r += 4) {
        const int row = row0 + r;
        if (row < N_NODES) {
            const float v = accum[r * N_OUT + lane];
            out[(size_t)row * N_OUT + lane] = v > 0.f ? v : expf(v) - 1.f;
        }
    }
}

extern "C" void kernel_launch(void* const* d_in, const int* in_sizes, int n_in,
                              void* d_out, int out_size, void* d_ws, size_t ws_size,
                              hipStream_t stream) {
    const float* x  = (const float*)d_in[0];
    const int*   er = (const int*)d_in[1];
    const int*   ec = (const int*)d_in[2];
    const float* ev = (const float*)d_in[3];
    const float* W  = (const float*)d_in[4];
    const float* b  = (const float*)d_in[5];
    float* out = (float*)d_out;
    char* ws = (char*)d_ws;

    unsigned short* hbf   = (unsigned short*)(ws + WS_HBF);
    unsigned short* wt    = (unsigned short*)(ws + WS_WT);
    unsigned short* gposT = (unsigned short*)(ws + WS_GP);   // aliases hbf
    unsigned short* histT = (unsigned short*)(ws + WS_HT);   // aliases edges
    int*  btot  = (int*)(ws + WS_BTOT);
    int*  boffs = (int*)(ws + WS_BOFF);
    int2* edges = (int2*)(ws + WS_EDGES);

    hist2_kernel<<<NBLK, 256, 0, stream>>>(er, histT);
    scanA_kernel<<<(NBUCKETS + 3) / 4, 256, 0, stream>>>(histT, gposT, btot);
    bscan_kernel<<<1, 1024, 0, stream>>>(btot, boffs);
    scat2_kernel<<<NBLK, 256, 0, stream>>>(er, ec, ev, gposT, boffs, edges);
    wconv_kernel<<<64, 256, 0, stream>>>(W, wt);
    gemm_kernel<<<(N_NODES + 63) / 64, 256, 0, stream>>>(x, (const float4*)wt, b, hbf);
    bagg_kernel<<<NBUCKETS, 256, 0, stream>>>(boffs, edges, hbf, out);
}